// Round 1
// baseline (1061.373 us; speedup 1.0000x reference)
//
#include <hip/hip_runtime.h>

#define H 448
#define W 448
#define CIN 64
#define COUT 64
#define NBATCH 4
#define BS 14      // output block (block stride)
#define NBY 32
#define NBX 32

// Transpose weight [cout][cin][3][3] -> wT[cin*9][cout] so that lanes (=cout)
// read consecutive addresses.
__global__ __launch_bounds__(256) void prep_wT(const float* __restrict__ w,
                                               float* __restrict__ wT) {
  int i = blockIdx.x * 256 + threadIdx.x;
  if (i < COUT * CIN * 9) {
    int co = i / (CIN * 9);
    int rem = i - co * (CIN * 9);   // c*9 + ky*3 + kx
    wT[rem * COUT + co] = w[i];
  }
}

__global__ __launch_bounds__(256) void sbnet_conv(
    const float* __restrict__ x, const float* __restrict__ mask,
    const float* __restrict__ wT, const float* __restrict__ bias,
    float* __restrict__ out) {
  const int bx = blockIdx.x, by = blockIdx.y, n = blockIdx.z;
  const int t = threadIdx.x;

  // 64 KB: input tile [c][16][16]; reused as transpose buffer in epilogue.
  __shared__ float tile[CIN * 16 * 16];

  // ---- activity: max over 16x16 mask window (offset -1), -inf OOB ----
  {
    int wy = t >> 4, wx = t & 15;
    int my = by * BS - 1 + wy, mx = bx * BS - 1 + wx;
    int inb = (my >= 0 && my < H && mx >= 0 && mx < W);
    float v = inb ? mask[(n * H + my) * W + mx] : -1.f;
    int p = inb && (v > 0.5f);
    int active = __syncthreads_or(p);
    if (!active) {
      // zero-fill this output block (d_out is poisoned before each launch)
      for (int i = t; i < COUT * BS * BS; i += 256) {
        int cc = i / (BS * BS);
        int pp = i - cc * (BS * BS);
        int yy = pp / BS, xx = pp - yy * BS;
        out[((size_t)(n * COUT + cc) * H + by * BS + yy) * W + bx * BS + xx] =
            0.f;
      }
      return;
    }
  }

  // ---- stage input halo tile [c][16][16], zero-padded at borders ----
  for (int i = t; i < CIN * 256; i += 256) {
    int c = i >> 8;
    int wy = (i >> 4) & 15, wx = i & 15;
    int my = by * BS - 1 + wy, mx = bx * BS - 1 + wx;
    float v = 0.f;
    if (my >= 0 && my < H && mx >= 0 && mx < W)
      v = x[((size_t)(n * CIN + c) * H + my) * W + mx];
    tile[i] = v;
  }
  __syncthreads();

  // ---- compute: wave g owns output rows r0..r0+nr-1, lane = cout ----
  const int g = t >> 6;          // wave id 0..3
  const int co = t & 63;         // cout for this lane
  const int r0 = g * 4;
  const int nr = (g < 3) ? 4 : 2;  // rows per wave (14 = 4+4+4+2)

  float acc[4][14];
#pragma unroll
  for (int r = 0; r < 4; ++r)
#pragma unroll
    for (int s = 0; s < 14; ++s) acc[r][s] = 0.f;

#pragma unroll 1
  for (int c = 0; c < CIN; ++c) {
    // 9 weights for (c, lane's cout): coalesced 256B loads, L1/L2-hot
    float wv[9];
    const float* wp = wT + c * 9 * COUT + co;
#pragma unroll
    for (int k = 0; k < 9; ++k) wv[k] = wp[k * COUT];

    const float4* trow = (const float4*)(tile + c * 256);
#pragma unroll
    for (int ir = 0; ir < 6; ++ir) {       // tile rows r0 .. r0+nr+1
      if (ir < nr + 2) {                   // wave-uniform
        float4 q0 = trow[(r0 + ir) * 4 + 0];  // all lanes same addr: broadcast
        float4 q1 = trow[(r0 + ir) * 4 + 1];
        float4 q2 = trow[(r0 + ir) * 4 + 2];
        float4 q3 = trow[(r0 + ir) * 4 + 3];
        float row[16] = {q0.x, q0.y, q0.z, q0.w, q1.x, q1.y, q1.z, q1.w,
                         q2.x, q2.y, q2.z, q2.w, q3.x, q3.y, q3.z, q3.w};
#pragma unroll
        for (int ky = 0; ky < 3; ++ky) {
          int r = ir - ky;                 // relative output row fed by this ky
          if (r >= 0 && r < 4) {
            if (r < nr) {                  // wave-uniform
#pragma unroll
              for (int kx = 0; kx < 3; ++kx)
#pragma unroll
                for (int s = 0; s < 14; ++s)
                  acc[r][s] = fmaf(row[s + kx], wv[ky * 3 + kx], acc[r][s]);
            }
          }
        }
      }
    }
  }

  // ---- epilogue: transpose via LDS for coalesced stores ----
  __syncthreads();  // everyone done reading tile before we overwrite it
  const float bv = bias[co];
#pragma unroll
  for (int r = 0; r < 4; ++r) {
    if (r < nr) {
#pragma unroll
      for (int s = 0; s < 14; ++s)
        tile[co * 197 + (r0 + r) * 14 + s] = acc[r][s] + bv;  // stride 197: 2-way max
    }
  }
  __syncthreads();
  for (int i = t; i < COUT * 196; i += 256) {
    int cc = i / 196;
    int pp = i - cc * 196;
    int yy = pp / 14, xx = pp - yy * 14;
    out[((size_t)(n * COUT + cc) * H + by * BS + yy) * W + bx * BS + xx] =
        tile[cc * 197 + pp];
  }
}

extern "C" void kernel_launch(void* const* d_in, const int* in_sizes, int n_in,
                              void* d_out, int out_size, void* d_ws,
                              size_t ws_size, hipStream_t stream) {
  const float* x = (const float*)d_in[0];     // [4,64,448,448] f32
  const float* mask = (const float*)d_in[1];  // [4,1,448,448] f32
  const float* w = (const float*)d_in[2];     // [64,64,3,3] f32
  const float* bias = (const float*)d_in[3];  // [64] f32
  float* out = (float*)d_out;                 // [4,64,448,448] f32
  float* wT = (float*)d_ws;                   // 147456 B scratch

  prep_wT<<<dim3((COUT * CIN * 9 + 255) / 256), 256, 0, stream>>>(w, wT);
  sbnet_conv<<<dim3(NBX, NBY, NBATCH), 256, 0, stream>>>(x, mask, wT, bias,
                                                         out);
}

// Round 2
// 509.801 us; speedup vs baseline: 2.0819x; 2.0819x over previous
//
#include <hip/hip_runtime.h>

#define H 448
#define W 448
#define CIN 64
#define COUT 64
#define NBATCH 4
#define BS 14      // output block (block stride)
#define NBY 32
#define NBX 32
#define HW (H * W)
#define PITCH 72   // bf16 elems per pixel row in LDS A-tile (16B aligned, bank-balanced)

typedef __attribute__((ext_vector_type(8))) short short8;
typedef __attribute__((ext_vector_type(4))) float f32x4;

static __device__ __forceinline__ unsigned short f2bf(float f) {
  unsigned u = __float_as_uint(f);
  u += 0x7FFF + ((u >> 16) & 1);  // RNE
  return (unsigned short)(u >> 16);
}

// Pack weights into B-fragment order:
// wB[((kk*4 + nt)*64 + lane)*8 + j] = bf16(W[k][n]),
//   k = kk*32 + (lane>>4)*8 + j  (k = tap*64 + c),  n = nt*16 + (lane&15),
//   W[k][n] = w[n][c][tap].
__global__ __launch_bounds__(256) void prep_wB(const float* __restrict__ w,
                                               unsigned short* __restrict__ wB) {
  int e = blockIdx.x * 256 + threadIdx.x;
  if (e >= 18 * 4 * 64 * 8) return;
  int j = e & 7, lane = (e >> 3) & 63, nt = (e >> 9) & 3, kk = e >> 11;
  int k = kk * 32 + (lane >> 4) * 8 + j;
  int tap = k >> 6, c = k & 63;
  int n = nt * 16 + (lane & 15);
  wB[e] = f2bf(w[(n * CIN + c) * 9 + tap]);
}

__global__ __launch_bounds__(256) void sbnet_conv(
    const float* __restrict__ x, const float* __restrict__ mask,
    const unsigned short* __restrict__ wB, const float* __restrict__ bias,
    float* __restrict__ out) {
  const int bx = blockIdx.x, by = blockIdx.y, n = blockIdx.z;
  const int t = threadIdx.x;

  // 36 KB: bf16 A-tile [256 pixels][PITCH]; reused as f32 transpose buf in epilogue.
  __shared__ short tileS[256 * PITCH];

  // ---- activity: max over 16x16 mask window (offset -1), -inf OOB ----
  {
    int wy = t >> 4, wx = t & 15;
    int my = by * BS - 1 + wy, mx = bx * BS - 1 + wx;
    int inb = (my >= 0 && my < H && mx >= 0 && mx < W);
    float v = inb ? mask[(n * H + my) * W + mx] : -1.f;
    int p = inb && (v > 0.5f);
    int active = __syncthreads_or(p);
    if (!active) {
      for (int i = t; i < COUT * BS * BS; i += 256) {
        int cc = i / (BS * BS);
        int pp = i - cc * (BS * BS);
        int yy = pp / BS, xx = pp - yy * BS;
        out[((size_t)(n * COUT + cc) * H + by * BS + yy) * W + bx * BS + xx] =
            0.f;
      }
      return;
    }
  }

  // ---- stage halo tile -> LDS bf16 [pix][c], pitch 72 ----
  {
    const int pix = t;  // 0..255, (iy,ix) in 16x16
    int iy = pix >> 4, ix = pix & 15;
    int gy = by * BS - 1 + iy, gx = bx * BS - 1 + ix;
    bool inb = (gy >= 0 && gy < H && gx >= 0 && gx < W);
    const float* xp = x + (size_t)n * CIN * HW + (inb ? (gy * W + gx) : 0);
#pragma unroll
    for (int cc = 0; cc < 8; ++cc) {  // chunks of 8 channels
      float v[8];
#pragma unroll
      for (int j = 0; j < 8; ++j)
        v[j] = inb ? xp[(size_t)(cc * 8 + j) * HW] : 0.f;
      int4 pk;
      pk.x = (int)f2bf(v[0]) | ((int)f2bf(v[1]) << 16);
      pk.y = (int)f2bf(v[2]) | ((int)f2bf(v[3]) << 16);
      pk.z = (int)f2bf(v[4]) | ((int)f2bf(v[5]) << 16);
      pk.w = (int)f2bf(v[6]) | ((int)f2bf(v[7]) << 16);
      *(int4*)(tileS + pix * PITCH + cc * 8) = pk;
    }
  }
  __syncthreads();

  // ---- MFMA main loop: wave wv owns M-tiles {wv, wv+4, wv+8, (wv+12)} ----
  const int wv = t >> 6, lane = t & 63;
  const int quad = lane >> 4, lrow = lane & 15;
  const int nmt = (wv == 0) ? 4 : 3;  // 13 M-tiles of 16 pixels (196 padded)
  const int qoff = quad * 8;

  // per-lane A base offsets (bf16 units) for each owned M-tile
  int abase[4];
#pragma unroll
  for (int i = 0; i < 4; ++i) {
    int mt = wv + 4 * i;
    int m = mt * 16 + lrow;
    if (m > 195) m = 195;  // clamp tail (broadcast, masked at store)
    int oy = m / 14, ox = m - oy * 14;
    abase[i] = (oy * 16 + ox) * PITCH;
  }

  f32x4 acc[4][4];
#pragma unroll
  for (int i = 0; i < 4; ++i)
#pragma unroll
    for (int nt = 0; nt < 4; ++nt) acc[i][nt] = (f32x4){0.f, 0.f, 0.f, 0.f};

  const short8* wB8 = (const short8*)wB;
  short8 bnxt[4];
#pragma unroll
  for (int nt = 0; nt < 4; ++nt) bnxt[nt] = wB8[nt * 64 + lane];

#pragma unroll 2
  for (int kk = 0; kk < 18; ++kk) {
    short8 bcur[4];
#pragma unroll
    for (int nt = 0; nt < 4; ++nt) bcur[nt] = bnxt[nt];
    if (kk < 17) {
#pragma unroll
      for (int nt = 0; nt < 4; ++nt)
        bnxt[nt] = wB8[((kk + 1) * 4 + nt) * 64 + lane];
    }
    int tap = kk >> 1;
    int ky = tap / 3, kx = tap - 3 * ky;
    int ko = (ky * 16 + kx) * PITCH + (kk & 1) * 32 + qoff;
#pragma unroll
    for (int i = 0; i < 4; ++i) {
      if (i < nmt) {
        short8 av = *(const short8*)(tileS + abase[i] + ko);
#pragma unroll
        for (int nt = 0; nt < 4; ++nt)
          acc[i][nt] = __builtin_amdgcn_mfma_f32_16x16x32_bf16(av, bcur[nt],
                                                               acc[i][nt], 0,
                                                               0, 0);
      }
    }
  }

  // ---- epilogue: 2 passes of 32 couts, transpose via LDS, coalesced store ----
  float* ldsF = (float*)tileS;  // [32][200] f32 = 25.6 KB (fits in 36 KB)
#pragma unroll 1
  for (int p = 0; p < 2; ++p) {
    __syncthreads();  // A-tile reads / previous pass copy done
#pragma unroll
    for (int i = 0; i < 4; ++i) {
      if (i < nmt) {
        int mt = wv + 4 * i;
        int m0 = mt * 16 + quad * 4;
        bool full = (mt < 12) || (quad == 0);  // tail tile: only quad 0 valid
        if (full) {
#pragma unroll
          for (int q2 = 0; q2 < 2; ++q2) {
            int nt = 2 * p + q2;
            int cout_l = q2 * 16 + lrow;
            float4 vv;
            vv.x = acc[i][nt][0];
            vv.y = acc[i][nt][1];
            vv.z = acc[i][nt][2];
            vv.w = acc[i][nt][3];
            *(float4*)(ldsF + cout_l * 200 + m0) = vv;
          }
        }
      }
    }
    __syncthreads();
    for (int idx = t; idx < 32 * 196; idx += 256) {
      int co_l = idx / 196;
      int pp = idx - co_l * 196;
      int cout = p * 32 + co_l;
      int oy = pp / 14, ox = pp - oy * 14;
      out[((size_t)(n * COUT + cout) * H + by * BS + oy) * W + bx * BS + ox] =
          ldsF[co_l * 200 + pp] + bias[cout];
    }
  }
}

extern "C" void kernel_launch(void* const* d_in, const int* in_sizes, int n_in,
                              void* d_out, int out_size, void* d_ws,
                              size_t ws_size, hipStream_t stream) {
  const float* x = (const float*)d_in[0];     // [4,64,448,448] f32
  const float* mask = (const float*)d_in[1];  // [4,1,448,448] f32
  const float* w = (const float*)d_in[2];     // [64,64,3,3] f32
  const float* bias = (const float*)d_in[3];  // [64] f32
  float* out = (float*)d_out;                 // [4,64,448,448] f32
  unsigned short* wB = (unsigned short*)d_ws; // 73728 B scratch

  prep_wB<<<dim3((18 * 4 * 64 * 8 + 255) / 256), 256, 0, stream>>>(w, wB);
  sbnet_conv<<<dim3(NBX, NBY, NBATCH), 256, 0, stream>>>(x, mask, wB, bias,
                                                         out);
}